// Round 2
// baseline (9562.099 us; speedup 1.0000x reference)
//
#include <hip/hip_runtime.h>
#include <hip/hip_bf16.h>
#include <cstdint>
#include <cstddef>

// ---------------------------------------------------------------------------
// Mamba2 encoder, MI355X. Round 2: dtype-robust correctness build.
//   - probe kernel detects whether d_in tensors are fp32 or bf16
//   - all inputs canonicalized into workspace (bf16 weights, fp32 dt params)
//   - GEMMs via mfma_f32_16x16x32_bf16, 64x64 tile, LDS staged
//   - SSM scan: 1 block per (b,head), fp32 state in registers
// ---------------------------------------------------------------------------

#define B_      16
#define L_      1024
#define NTOK    (B_ * L_)      // 16384
#define DMODEL  512
#define DINNER  1024
#define NHEADS  16
#define HEADDIM 64
#define DSTATE  128
#define CONVDIM 1280           // DINNER + 2*DSTATE
#define DINPROJ 2320           // 2*DINNER + 2*DSTATE + NHEADS
#define NPAD    2368           // 37*64, padded in_proj N
#define NLAYERS 6

typedef short s8v  __attribute__((ext_vector_type(8)));
typedef float f4v  __attribute__((ext_vector_type(4)));
typedef unsigned short u8v __attribute__((ext_vector_type(8)));

__device__ __forceinline__ float b2f(unsigned short u) {
  unsigned v = ((unsigned)u) << 16;
  return __builtin_bit_cast(float, v);
}
__device__ __forceinline__ unsigned short f2b(float f) {
  unsigned u = __builtin_bit_cast(unsigned, f);
  u += 0x7fffu + ((u >> 16) & 1u);
  return (unsigned short)(u >> 16);
}

// ---------------- dtype probe: ln_g[0] == 1.0 ------------------------------
__global__ void k_flag(const unsigned int* __restrict__ lng_raw, int* __restrict__ flag) {
  // fp32 1.0f -> 0x3F800000 ; two bf16 1.0 -> 0x3F803F80
  *flag = (lng_raw[0] == 0x3F800000u) ? 0 : 1;
}

// ---------------- canonicalize: any -> bf16 --------------------------------
__global__ __launch_bounds__(256) void k_convert(
    const void* __restrict__ src, unsigned short* __restrict__ dst,
    const int n, const int* __restrict__ flag)
{
  const int f = *flag;
  for (int i = blockIdx.x * 256 + threadIdx.x; i < n; i += gridDim.x * 256)
    dst[i] = f ? ((const unsigned short*)src)[i] : f2b(((const float*)src)[i]);
}

// ---------------- canonicalize: any -> fp32 --------------------------------
__global__ __launch_bounds__(256) void k_convertf(
    const void* __restrict__ src, float* __restrict__ dst,
    const int n, const int* __restrict__ flag)
{
  const int f = *flag;
  for (int i = blockIdx.x * 256 + threadIdx.x; i < n; i += gridDim.x * 256)
    dst[i] = f ? b2f(((const unsigned short*)src)[i]) : ((const float*)src)[i];
}

// ---------------- canonicalize in_proj_w with column pad to NPAD -----------
__global__ __launch_bounds__(256) void k_convert_pad(
    const void* __restrict__ src, unsigned short* __restrict__ dst,
    const int* __restrict__ flag)
{
  const int n = NLAYERS * DMODEL * NPAD;
  const int f = *flag;
  for (int i = blockIdx.x * 256 + threadIdx.x; i < n; i += gridDim.x * 256) {
    const int row = i / NPAD, col = i - row * NPAD;
    unsigned short v = 0;
    if (col < DINPROJ) {
      const size_t s = (size_t)row * DINPROJ + col;
      v = f ? ((const unsigned short*)src)[s] : f2b(((const float*)src)[s]);
    }
    dst[i] = v;
  }
}

// ---------------- prologue: x = rope(states @ W + b) -----------------------
__global__ __launch_bounds__(256) void k_inproj_rope(
    const unsigned short* __restrict__ states,  // canonical bf16 [NTOK,17]
    const unsigned short* __restrict__ W,       // [17,512]
    const unsigned short* __restrict__ bias,    // [512]
    float* __restrict__ X)                      // [NTOK,512] fp32
{
  const int tok = blockIdx.x;
  const int t   = threadIdx.x;          // pair index 0..255
  __shared__ float s[17];
  if (t < 17) s[t] = b2f(states[tok * 17 + t]);
  __syncthreads();
  const int d0 = 2 * t, d1 = d0 + 1;
  float x1 = b2f(bias[d0]);
  float x2 = b2f(bias[d1]);
  #pragma unroll
  for (int k = 0; k < 17; k++) {
    float sv = s[k];
    x1 = fmaf(sv, b2f(W[k * DMODEL + d0]), x1);
    x2 = fmaf(sv, b2f(W[k * DMODEL + d1]), x2);
  }
  const int l = tok & (L_ - 1);
  float invf = expf(-((float)d0 / (float)DMODEL) * 9.2103403719761836f);
  float fr = (float)l * invf;
  float sn, c;
  sincosf(fr, &sn, &c);
  X[(size_t)tok * DMODEL + d0] = x1 * c - x2 * sn;
  X[(size_t)tok * DMODEL + d1] = x1 * sn + x2 * c;
}

// ---------------- layernorm (fp32 in, bf16 out) ----------------------------
__global__ __launch_bounds__(64) void k_layernorm(
    const float* __restrict__ X,
    const unsigned short* __restrict__ g,
    const unsigned short* __restrict__ b,
    unsigned short* __restrict__ out)   // [NTOK,512] bf16
{
  const int tok = blockIdx.x;
  const int t   = threadIdx.x;          // 64
  const float* row = X + (size_t)tok * DMODEL;
  float4 v0 = *(const float4*)(row + t * 4);
  float4 v1 = *(const float4*)(row + 256 + t * 4);
  float s  = v0.x + v0.y + v0.z + v0.w + v1.x + v1.y + v1.z + v1.w;
  float sq = v0.x*v0.x + v0.y*v0.y + v0.z*v0.z + v0.w*v0.w
           + v1.x*v1.x + v1.y*v1.y + v1.z*v1.z + v1.w*v1.w;
  #pragma unroll
  for (int m = 1; m < 64; m <<= 1) { s += __shfl_xor(s, m); sq += __shfl_xor(sq, m); }
  float mu  = s  * (1.f / DMODEL);
  float var = sq * (1.f / DMODEL) - mu * mu;
  float rs  = rsqrtf(var + 1e-5f);
  {
    int c = t * 4;
    ushort4 o;
    o.x = f2b((v0.x - mu) * rs * b2f(g[c+0]) + b2f(b[c+0]));
    o.y = f2b((v0.y - mu) * rs * b2f(g[c+1]) + b2f(b[c+1]));
    o.z = f2b((v0.z - mu) * rs * b2f(g[c+2]) + b2f(b[c+2]));
    o.w = f2b((v0.w - mu) * rs * b2f(g[c+3]) + b2f(b[c+3]));
    *(ushort4*)(out + (size_t)tok * DMODEL + c) = o;
  }
  {
    int c = 256 + t * 4;
    ushort4 o;
    o.x = f2b((v1.x - mu) * rs * b2f(g[c+0]) + b2f(b[c+0]));
    o.y = f2b((v1.y - mu) * rs * b2f(g[c+1]) + b2f(b[c+1]));
    o.z = f2b((v1.z - mu) * rs * b2f(g[c+2]) + b2f(b[c+2]));
    o.w = f2b((v1.w - mu) * rs * b2f(g[c+3]) + b2f(b[c+3]));
    *(ushort4*)(out + (size_t)tok * DMODEL + c) = o;
  }
}

// ---------------- fp32 GEMV for the 16 dt columns (precision-critical) -----
__global__ __launch_bounds__(64) void k_dtgemv(
    const float* __restrict__ X,                // residual stream fp32
    const unsigned short* __restrict__ g,
    const unsigned short* __restrict__ b,
    const unsigned short* __restrict__ W,       // canonical padded [512,NPAD]
    float* __restrict__ dtraw)                  // [NTOK,16] fp32
{
  const int tok = blockIdx.x;
  const int t   = threadIdx.x;  // 64
  __shared__ __align__(16) float sx[DMODEL];
  const float* row = X + (size_t)tok * DMODEL;
  float4 v0 = *(const float4*)(row + t * 4);
  float4 v1 = *(const float4*)(row + 256 + t * 4);
  *(float4*)&sx[t * 4]       = v0;
  *(float4*)&sx[256 + t * 4] = v1;
  float s  = v0.x + v0.y + v0.z + v0.w + v1.x + v1.y + v1.z + v1.w;
  float sq = v0.x*v0.x + v0.y*v0.y + v0.z*v0.z + v0.w*v0.w
           + v1.x*v1.x + v1.y*v1.y + v1.z*v1.z + v1.w*v1.w;
  #pragma unroll
  for (int m = 1; m < 64; m <<= 1) { s += __shfl_xor(s, m); sq += __shfl_xor(sq, m); }
  float mu  = s  * (1.f / DMODEL);
  float var = sq * (1.f / DMODEL) - mu * mu;
  float rs  = rsqrtf(var + 1e-5f);
  __syncthreads();
  const int hc = t & 15;        // dt head column
  const int kq = t >> 4;        // K quarter
  float acc = 0.f;
  for (int k = kq * 128; k < kq * 128 + 128; k++) {
    float xn = (sx[k] - mu) * rs * b2f(g[k]) + b2f(b[k]);
    acc = fmaf(xn, b2f(W[(size_t)k * NPAD + 2304 + hc]), acc);
  }
  acc += __shfl_xor(acc, 16);
  acc += __shfl_xor(acc, 32);
  if (kq == 0) dtraw[(size_t)tok * NHEADS + hc] = acc;
}

// ---------------- MFMA bf16 GEMM: C[M,N] = A[M,K] @ W[K,N] -----------------
// MODE 0: in_proj (N=NPAD)  -> bf16 store cols <2304 into [M,DINPROJ] buffer
// MODE 1: out_proj          -> resid[m*N+n] += v   (fp32 residual accumulate)
// MODE 2: final             -> out = v + bias[n]   (bf16 or fp32 per flag)
template<int MODE>
__global__ __launch_bounds__(256) void k_gemm(
    const unsigned short* __restrict__ A,
    const unsigned short* __restrict__ W,
    const int M, const int N, const int K,
    unsigned short* __restrict__ outb,
    float* __restrict__ resid,
    const unsigned short* __restrict__ bias,
    const int* __restrict__ flag)
{
  __shared__ __align__(16) short a_sh[64][40];  // +8 pad
  __shared__ __align__(16) short b_sh[64][40];  // transposed: [n][k]
  const int t    = threadIdx.x;
  const int m0   = blockIdx.y * 64;
  const int n0   = blockIdx.x * 64;
  const int wv   = t >> 6;
  const int lane = t & 63;
  const int l16  = lane & 15;
  const int quad = lane >> 4;
  const int am = t >> 2, ak = (t & 3) << 3;   // A stage
  const int bk = t >> 3, bn = (t & 7) << 3;   // B stage
  f4v acc[4] = {};
  for (int k0 = 0; k0 < K; k0 += 32) {
    s8v av = *(const s8v*)(A + (size_t)(m0 + am) * K + k0 + ak);
    *(s8v*)(&a_sh[am][ak]) = av;
    s8v bv = *(const s8v*)(W + (size_t)(k0 + bk) * N + n0 + bn);
    #pragma unroll
    for (int j = 0; j < 8; j++) b_sh[bn + j][bk] = bv[j];
    __syncthreads();
    const s8v af = *(const s8v*)(&a_sh[wv * 16 + l16][quad * 8]);
    #pragma unroll
    for (int nt = 0; nt < 4; nt++) {
      const s8v bf = *(const s8v*)(&b_sh[nt * 16 + l16][quad * 8]);
      acc[nt] = __builtin_amdgcn_mfma_f32_16x16x32_bf16(af, bf, acc[nt], 0, 0, 0);
    }
    __syncthreads();
  }
  const int fv = (MODE == 2) ? *flag : 0;
  #pragma unroll
  for (int nt = 0; nt < 4; nt++) {
    #pragma unroll
    for (int r = 0; r < 4; r++) {
      const int m = m0 + wv * 16 + quad * 4 + r;   // C/D row
      const int n = n0 + nt * 16 + l16;            // C/D col
      float v = acc[nt][r];
      if (MODE == 0) {
        if (n < 2304) outb[(size_t)m * DINPROJ + n] = f2b(v);
      } else if (MODE == 1) {
        resid[(size_t)m * N + n] += v;
      } else {
        v += b2f(bias[n]);
        if (fv) outb[(size_t)m * N + n] = f2b(v);
        else    ((float*)resid)[(size_t)m * N + n] = v;
      }
    }
  }
}

// ---------------- causal conv1d (K=4) + silu -> bf16 -----------------------
__global__ __launch_bounds__(256) void k_conv(
    const unsigned short* __restrict__ zx,   // zxbcdt bf16 [NTOK,DINPROJ]
    const unsigned short* __restrict__ cw,   // canonical conv_w[l] [1280,4]
    const unsigned short* __restrict__ cb,   // canonical conv_b[l] [1280]
    unsigned short* __restrict__ out)        // [NTOK,1280] bf16
{
  const int c   = blockIdx.x * 256 + threadIdx.x;  // 0..1279
  const int tok = blockIdx.y;
  const int l   = tok & (L_ - 1);
  const int base = tok - l;
  float acc = b2f(cb[c]);
  #pragma unroll
  for (int k = 0; k < 4; k++) {
    const int li = l + k - 3;
    if (li >= 0)
      acc = fmaf(b2f(zx[(size_t)(base + li) * DINPROJ + DINNER + c]),
                 b2f(cw[c * 4 + k]), acc);
  }
  out[(size_t)tok * CONVDIM + c] = f2b(acc / (1.f + expf(-acc)));   // silu
}

// ---------------- dt = softplus(raw + bias); decay = exp(dt * -exp(Alog)) --
__global__ __launch_bounds__(256) void k_dtdecay(
    const float* __restrict__ raw,
    const float* __restrict__ dtb,    // fp32 canonical [16]
    const float* __restrict__ alog,   // fp32 canonical [16]
    float* __restrict__ DT, float* __restrict__ DEC)
{
  const int idx = blockIdx.x * 256 + threadIdx.x;   // NTOK*16
  const int h = idx & 15;
  float x = raw[idx] + dtb[h];
  float dt = (x > 20.f) ? x : log1pf(expf(x));
  float A = -expf(alog[h]);
  DT[idx] = dt;
  DEC[idx] = expf(dt * A);
}

// ---------------- sequential SSM scan: one block per (b, head) -------------
__global__ __launch_bounds__(256) void k_scan(
    const unsigned short* __restrict__ xbc,  // conv out bf16 [NTOK,1280]
    const float* __restrict__ DT,
    const float* __restrict__ DEC,
    const float* __restrict__ Dp,            // fp32 canonical [16]
    unsigned short* __restrict__ yout)       // BUF1, writes cols 1024..2048
{
  const int bh = blockIdx.x;
  const int b  = bh >> 4, h = bh & 15;
  const int t  = threadIdx.x;
  __shared__ __align__(16) float sxbc[320];  // [0,64)=x  [64,192)=B  [192,320)=C
  __shared__ float ssc[2];
  const int ngrp = t & 15, pgrp = t >> 4;
  const int n0 = ngrp * 8, p0 = pgrp * 4;
  float hs[4][8] = {};
  const float Dh = Dp[h];
  for (int ts = 0; ts < L_; ts++) {
    const int tok = (b << 10) + ts;
    if (t < 40) {
      const int j = t * 8;
      const int col = (j < 64) ? (h * HEADDIM + j) : (960 + j);
      u8v v = *(const u8v*)(xbc + (size_t)tok * CONVDIM + col);
      float* d = &sxbc[j];
      #pragma unroll
      for (int q = 0; q < 8; q++) d[q] = b2f(v[q]);
    }
    if (t == 63) {
      ssc[0] = DT[(size_t)tok * NHEADS + h];
      ssc[1] = DEC[(size_t)tok * NHEADS + h];
    }
    __syncthreads();
    float xa0 = sxbc[p0+0], xa1 = sxbc[p0+1], xa2 = sxbc[p0+2], xa3 = sxbc[p0+3];
    float Bv[8], Cv[8];
    #pragma unroll
    for (int q = 0; q < 8; q++) { Bv[q] = sxbc[64 + n0 + q]; Cv[q] = sxbc[192 + n0 + q]; }
    const float dts = ssc[0], dec = ssc[1];
    float xa[4] = {xa0, xa1, xa2, xa3};
    float yp[4];
    #pragma unroll
    for (int p = 0; p < 4; p++) {
      const float dtx = dts * xa[p];
      float a = 0.f;
      #pragma unroll
      for (int n = 0; n < 8; n++) {
        hs[p][n] = fmaf(hs[p][n], dec, dtx * Bv[n]);
        a = fmaf(hs[p][n], Cv[n], a);
      }
      yp[p] = a;
    }
    #pragma unroll
    for (int m = 1; m < 16; m <<= 1) {
      #pragma unroll
      for (int p = 0; p < 4; p++) yp[p] += __shfl_xor(yp[p], m);
    }
    if (ngrp == 0) {
      ushort4 o;
      o.x = f2b(yp[0] + Dh * xa[0]);
      o.y = f2b(yp[1] + Dh * xa[1]);
      o.z = f2b(yp[2] + Dh * xa[2]);
      o.w = f2b(yp[3] + Dh * xa[3]);
      *(ushort4*)(yout + (size_t)tok * DINPROJ + DINNER + h * HEADDIM + p0) = o;
    }
    __syncthreads();
  }
}

// ---------------- y*silu(z) -> RMSnorm*rms_w -> bf16 -----------------------
__global__ __launch_bounds__(256) void k_gate_rms(
    const unsigned short* __restrict__ buf1,  // z cols 0..1024, y cols 1024..2048
    const unsigned short* __restrict__ rmsw,
    unsigned short* __restrict__ out)         // [NTOK,1024] bf16
{
  const int tok = blockIdx.x;
  const int t   = threadIdx.x;
  const int c   = t * 4;
  ushort4 z4 = *(const ushort4*)(buf1 + (size_t)tok * DINPROJ + c);
  ushort4 y4 = *(const ushort4*)(buf1 + (size_t)tok * DINPROJ + DINNER + c);
  const unsigned short* za = (const unsigned short*)&z4;
  const unsigned short* ya = (const unsigned short*)&y4;
  float gv[4];
  #pragma unroll
  for (int j = 0; j < 4; j++) {
    float z = b2f(za[j]), y = b2f(ya[j]);
    gv[j] = y * (z / (1.f + expf(-z)));
  }
  float sq = gv[0]*gv[0] + gv[1]*gv[1] + gv[2]*gv[2] + gv[3]*gv[3];
  #pragma unroll
  for (int m = 1; m < 64; m <<= 1) sq += __shfl_xor(sq, m);
  __shared__ float sm[4];
  if ((t & 63) == 0) sm[t >> 6] = sq;
  __syncthreads();
  float rs = rsqrtf((sm[0] + sm[1] + sm[2] + sm[3]) * (1.f / DINNER) + 1e-5f);
  ushort4 o;
  unsigned short* oa = (unsigned short*)&o;
  #pragma unroll
  for (int j = 0; j < 4; j++) oa[j] = f2b(gv[j] * rs * b2f(rmsw[c + j]));
  *(ushort4*)(out + (size_t)tok * DINNER + c) = o;
}

// ---------------------------------------------------------------------------
extern "C" void kernel_launch(void* const* d_in, const int* in_sizes, int n_in,
                              void* d_out, int out_size, void* d_ws, size_t ws_size,
                              hipStream_t stream)
{
  (void)in_sizes; (void)n_in; (void)out_size; (void)ws_size;

  // ---- workspace carve (~176.7 MB), every region fully rewritten each call
  char* ws = (char*)d_ws;
  float*          X       = (float*)(ws);                        // 33,554,432 B
  unsigned short* BUF1    = (unsigned short*)(ws + 33554432);    // 76,021,760 B
  unsigned short* BUF2    = (unsigned short*)(ws + 109576192);   // 41,943,040 B
  float*          DTRAW   = (float*)(ws + 151519232);            //  1,048,576 B
  float*          DT      = (float*)(ws + 152567808);
  float*          DEC     = (float*)(ws + 153616384);
  unsigned short* CWIN    = (unsigned short*)(ws + 154664960);   // 14,548,992 B
  unsigned short* CWOUT   = (unsigned short*)(ws + 169213952);   //  6,291,456 B
  unsigned short* CWFIN   = (unsigned short*)(ws + 175505408);   //    524,288 B
  unsigned short* CIPW    = (unsigned short*)(ws + 176029696);   //     17,408 B
  unsigned short* CSTATES = (unsigned short*)(ws + 176047104);   //    557,056 B
  unsigned short* CSMALL  = (unsigned short*)(ws + 176604160);   //    105,472 B
  float*          CF32    = (float*)(ws + 176709632);            //      1,152 B
  int*            FLAG    = (int*)(ws + 176710784);
  unsigned short* HN      = BUF2;  // bf16 activations, reuses BUF2 region

  // CSMALL element offsets
  unsigned short* Cipb   = CSMALL + 0;
  unsigned short* Clng   = CSMALL + 512;
  unsigned short* Clnb   = CSMALL + 3584;
  unsigned short* Cconvw = CSMALL + 6656;
  unsigned short* Cconvb = CSMALL + 37376;
  unsigned short* Crmsw  = CSMALL + 45056;
  unsigned short* Cpostg = CSMALL + 51200;
  unsigned short* Cpostb = CSMALL + 51712;
  unsigned short* Cfinb  = CSMALL + 52224;
  float* Cdtb  = CF32 + 0;
  float* Calog = CF32 + 96;
  float* Cdpar = CF32 + 192;

  // ---- dtype probe + canonicalization ------------------------------------
  k_flag<<<1, 1, 0, stream>>>((const unsigned int*)d_in[3], FLAG);
  k_convert<<<512, 256, 0, stream>>>(d_in[0],  CSTATES, NTOK * 17, FLAG);
  k_convert<<<64, 256, 0, stream>>>(d_in[1],  CIPW,    17 * DMODEL, FLAG);
  k_convert<<<4,  256, 0, stream>>>(d_in[2],  Cipb,    DMODEL, FLAG);
  k_convert<<<16, 256, 0, stream>>>(d_in[3],  Clng,    NLAYERS * DMODEL, FLAG);
  k_convert<<<16, 256, 0, stream>>>(d_in[4],  Clnb,    NLAYERS * DMODEL, FLAG);
  k_convert_pad<<<2048, 256, 0, stream>>>(d_in[5], CWIN, FLAG);
  k_convert<<<128, 256, 0, stream>>>(d_in[6], Cconvw,  NLAYERS * CONVDIM * 4, FLAG);
  k_convert<<<32, 256, 0, stream>>>(d_in[7],  Cconvb,  NLAYERS * CONVDIM, FLAG);
  k_convertf<<<1, 256, 0, stream>>>(d_in[8],  Cdtb,    NLAYERS * NHEADS, FLAG);
  k_convertf<<<1, 256, 0, stream>>>(d_in[9],  Calog,   NLAYERS * NHEADS, FLAG);
  k_convertf<<<1, 256, 0, stream>>>(d_in[10], Cdpar,   NLAYERS * NHEADS, FLAG);
  k_convert<<<32, 256, 0, stream>>>(d_in[11], Crmsw,   NLAYERS * DINNER, FLAG);
  k_convert<<<2048, 256, 0, stream>>>(d_in[12], CWOUT, NLAYERS * DINNER * DMODEL, FLAG);
  k_convert<<<4,  256, 0, stream>>>(d_in[13], Cpostg,  DMODEL, FLAG);
  k_convert<<<4,  256, 0, stream>>>(d_in[14], Cpostb,  DMODEL, FLAG);
  k_convert<<<512, 256, 0, stream>>>(d_in[15], CWFIN,  DMODEL * DMODEL, FLAG);
  k_convert<<<4,  256, 0, stream>>>(d_in[16], Cfinb,   DMODEL, FLAG);

  // ---- network -------------------------------------------------------------
  k_inproj_rope<<<NTOK, 256, 0, stream>>>(CSTATES, CIPW, Cipb, X);

  for (int l = 0; l < NLAYERS; l++) {
    k_layernorm<<<NTOK, 64, 0, stream>>>(X, Clng + l * DMODEL, Clnb + l * DMODEL, HN);
    k_gemm<0><<<dim3(NPAD / 64, NTOK / 64), 256, 0, stream>>>(
        HN, CWIN + (size_t)l * DMODEL * NPAD, NTOK, NPAD, DMODEL,
        BUF1, nullptr, nullptr, FLAG);
    k_dtgemv<<<NTOK, 64, 0, stream>>>(
        X, Clng + l * DMODEL, Clnb + l * DMODEL,
        CWIN + (size_t)l * DMODEL * NPAD, DTRAW);
    k_conv<<<dim3(CONVDIM / 256, NTOK), 256, 0, stream>>>(
        BUF1, Cconvw + l * CONVDIM * 4, Cconvb + l * CONVDIM, BUF2);
    k_dtdecay<<<NTOK * NHEADS / 256, 256, 0, stream>>>(
        DTRAW, Cdtb + l * NHEADS, Calog + l * NHEADS, DT, DEC);
    k_scan<<<256, 256, 0, stream>>>(BUF2, DT, DEC, Cdpar + l * NHEADS, BUF1);
    k_gate_rms<<<NTOK, 256, 0, stream>>>(BUF1, Crmsw + l * DINNER, HN);
    k_gemm<1><<<dim3(DMODEL / 64, NTOK / 64), 256, 0, stream>>>(
        HN, CWOUT + (size_t)l * DINNER * DMODEL, NTOK, DMODEL, DINNER,
        nullptr, X, nullptr, FLAG);
  }

  k_layernorm<<<NTOK, 64, 0, stream>>>(X, Cpostg, Cpostb, HN);
  k_gemm<2><<<dim3(DMODEL / 64, NTOK / 64), 256, 0, stream>>>(
      HN, CWFIN, NTOK, DMODEL, DMODEL,
      (unsigned short*)d_out, (float*)d_out, Cfinb, FLAG);
}

// Round 3
// 5496.539 us; speedup vs baseline: 1.7397x; 1.7397x over previous
//
#include <hip/hip_runtime.h>
#include <hip/hip_bf16.h>
#include <cstdint>
#include <cstddef>

// ---------------------------------------------------------------------------
// Mamba2 encoder, MI355X. Round 3: chunked SSM scan (3-pass), rest unchanged.
//   - pass A: local scan per (b,h,chunk of 128), 2048 blocks (was 256)
//   - pass B: 8-step inter-chunk state propagation, element-parallel
//   - pass C: y += P_t * (C_t . h_start)  as MFMA GEMM per (b,h,chunk)
//   - ws_size guard: falls back to round-2 sequential scan if ws too small
// ---------------------------------------------------------------------------

#define B_      16
#define L_      1024
#define NTOK    (B_ * L_)      // 16384
#define DMODEL  512
#define DINNER  1024
#define NHEADS  16
#define HEADDIM 64
#define DSTATE  128
#define CONVDIM 1280           // DINNER + 2*DSTATE
#define DINPROJ 2320           // 2*DINNER + 2*DSTATE + NHEADS
#define NPAD    2368           // 37*64, padded in_proj N
#define NLAYERS 6
#define LC      128            // scan chunk length
#define NC      8              // chunks per sequence (L_/LC)

typedef short s8v  __attribute__((ext_vector_type(8)));
typedef float f4v  __attribute__((ext_vector_type(4)));
typedef unsigned short u8v __attribute__((ext_vector_type(8)));

__device__ __forceinline__ float b2f(unsigned short u) {
  unsigned v = ((unsigned)u) << 16;
  return __builtin_bit_cast(float, v);
}
__device__ __forceinline__ unsigned short f2b(float f) {
  unsigned u = __builtin_bit_cast(unsigned, f);
  u += 0x7fffu + ((u >> 16) & 1u);
  return (unsigned short)(u >> 16);
}

// ---------------- dtype probe: ln_g[0] == 1.0 ------------------------------
__global__ void k_flag(const unsigned int* __restrict__ lng_raw, int* __restrict__ flag) {
  *flag = (lng_raw[0] == 0x3F800000u) ? 0 : 1;   // fp32 1.0 vs two bf16 1.0
}

// ---------------- canonicalize: any -> bf16 --------------------------------
__global__ __launch_bounds__(256) void k_convert(
    const void* __restrict__ src, unsigned short* __restrict__ dst,
    const int n, const int* __restrict__ flag)
{
  const int f = *flag;
  for (int i = blockIdx.x * 256 + threadIdx.x; i < n; i += gridDim.x * 256)
    dst[i] = f ? ((const unsigned short*)src)[i] : f2b(((const float*)src)[i]);
}

// ---------------- canonicalize: any -> fp32 --------------------------------
__global__ __launch_bounds__(256) void k_convertf(
    const void* __restrict__ src, float* __restrict__ dst,
    const int n, const int* __restrict__ flag)
{
  const int f = *flag;
  for (int i = blockIdx.x * 256 + threadIdx.x; i < n; i += gridDim.x * 256)
    dst[i] = f ? b2f(((const unsigned short*)src)[i]) : ((const float*)src)[i];
}

// ---------------- canonicalize in_proj_w with column pad to NPAD -----------
__global__ __launch_bounds__(256) void k_convert_pad(
    const void* __restrict__ src, unsigned short* __restrict__ dst,
    const int* __restrict__ flag)
{
  const int n = NLAYERS * DMODEL * NPAD;
  const int f = *flag;
  for (int i = blockIdx.x * 256 + threadIdx.x; i < n; i += gridDim.x * 256) {
    const int row = i / NPAD, col = i - row * NPAD;
    unsigned short v = 0;
    if (col < DINPROJ) {
      const size_t s = (size_t)row * DINPROJ + col;
      v = f ? ((const unsigned short*)src)[s] : f2b(((const float*)src)[s]);
    }
    dst[i] = v;
  }
}

// ---------------- prologue: x = rope(states @ W + b) -----------------------
__global__ __launch_bounds__(256) void k_inproj_rope(
    const unsigned short* __restrict__ states,
    const unsigned short* __restrict__ W,
    const unsigned short* __restrict__ bias,
    float* __restrict__ X)
{
  const int tok = blockIdx.x;
  const int t   = threadIdx.x;
  __shared__ float s[17];
  if (t < 17) s[t] = b2f(states[tok * 17 + t]);
  __syncthreads();
  const int d0 = 2 * t, d1 = d0 + 1;
  float x1 = b2f(bias[d0]);
  float x2 = b2f(bias[d1]);
  #pragma unroll
  for (int k = 0; k < 17; k++) {
    float sv = s[k];
    x1 = fmaf(sv, b2f(W[k * DMODEL + d0]), x1);
    x2 = fmaf(sv, b2f(W[k * DMODEL + d1]), x2);
  }
  const int l = tok & (L_ - 1);
  float invf = expf(-((float)d0 / (float)DMODEL) * 9.2103403719761836f);
  float fr = (float)l * invf;
  float sn, c;
  sincosf(fr, &sn, &c);
  X[(size_t)tok * DMODEL + d0] = x1 * c - x2 * sn;
  X[(size_t)tok * DMODEL + d1] = x1 * sn + x2 * c;
}

// ---------------- layernorm (fp32 in, bf16 out) ----------------------------
__global__ __launch_bounds__(64) void k_layernorm(
    const float* __restrict__ X,
    const unsigned short* __restrict__ g,
    const unsigned short* __restrict__ b,
    unsigned short* __restrict__ out)
{
  const int tok = blockIdx.x;
  const int t   = threadIdx.x;
  const float* row = X + (size_t)tok * DMODEL;
  float4 v0 = *(const float4*)(row + t * 4);
  float4 v1 = *(const float4*)(row + 256 + t * 4);
  float s  = v0.x + v0.y + v0.z + v0.w + v1.x + v1.y + v1.z + v1.w;
  float sq = v0.x*v0.x + v0.y*v0.y + v0.z*v0.z + v0.w*v0.w
           + v1.x*v1.x + v1.y*v1.y + v1.z*v1.z + v1.w*v1.w;
  #pragma unroll
  for (int m = 1; m < 64; m <<= 1) { s += __shfl_xor(s, m); sq += __shfl_xor(sq, m); }
  float mu  = s  * (1.f / DMODEL);
  float var = sq * (1.f / DMODEL) - mu * mu;
  float rs  = rsqrtf(var + 1e-5f);
  {
    int c = t * 4;
    ushort4 o;
    o.x = f2b((v0.x - mu) * rs * b2f(g[c+0]) + b2f(b[c+0]));
    o.y = f2b((v0.y - mu) * rs * b2f(g[c+1]) + b2f(b[c+1]));
    o.z = f2b((v0.z - mu) * rs * b2f(g[c+2]) + b2f(b[c+2]));
    o.w = f2b((v0.w - mu) * rs * b2f(g[c+3]) + b2f(b[c+3]));
    *(ushort4*)(out + (size_t)tok * DMODEL + c) = o;
  }
  {
    int c = 256 + t * 4;
    ushort4 o;
    o.x = f2b((v1.x - mu) * rs * b2f(g[c+0]) + b2f(b[c+0]));
    o.y = f2b((v1.y - mu) * rs * b2f(g[c+1]) + b2f(b[c+1]));
    o.z = f2b((v1.z - mu) * rs * b2f(g[c+2]) + b2f(b[c+2]));
    o.w = f2b((v1.w - mu) * rs * b2f(g[c+3]) + b2f(b[c+3]));
    *(ushort4*)(out + (size_t)tok * DMODEL + c) = o;
  }
}

// ---------------- fp32 GEMV for the 16 dt columns (precision-critical) -----
__global__ __launch_bounds__(64) void k_dtgemv(
    const float* __restrict__ X,
    const unsigned short* __restrict__ g,
    const unsigned short* __restrict__ b,
    const unsigned short* __restrict__ W,       // canonical padded [512,NPAD]
    float* __restrict__ dtraw)
{
  const int tok = blockIdx.x;
  const int t   = threadIdx.x;
  __shared__ __align__(16) float sx[DMODEL];
  const float* row = X + (size_t)tok * DMODEL;
  float4 v0 = *(const float4*)(row + t * 4);
  float4 v1 = *(const float4*)(row + 256 + t * 4);
  *(float4*)&sx[t * 4]       = v0;
  *(float4*)&sx[256 + t * 4] = v1;
  float s  = v0.x + v0.y + v0.z + v0.w + v1.x + v1.y + v1.z + v1.w;
  float sq = v0.x*v0.x + v0.y*v0.y + v0.z*v0.z + v0.w*v0.w
           + v1.x*v1.x + v1.y*v1.y + v1.z*v1.z + v1.w*v1.w;
  #pragma unroll
  for (int m = 1; m < 64; m <<= 1) { s += __shfl_xor(s, m); sq += __shfl_xor(sq, m); }
  float mu  = s  * (1.f / DMODEL);
  float var = sq * (1.f / DMODEL) - mu * mu;
  float rs  = rsqrtf(var + 1e-5f);
  __syncthreads();
  const int hc = t & 15;
  const int kq = t >> 4;
  float acc = 0.f;
  for (int k = kq * 128; k < kq * 128 + 128; k++) {
    float xn = (sx[k] - mu) * rs * b2f(g[k]) + b2f(b[k]);
    acc = fmaf(xn, b2f(W[(size_t)k * NPAD + 2304 + hc]), acc);
  }
  acc += __shfl_xor(acc, 16);
  acc += __shfl_xor(acc, 32);
  if (kq == 0) dtraw[(size_t)tok * NHEADS + hc] = acc;
}

// ---------------- MFMA bf16 GEMM: C[M,N] = A[M,K] @ W[K,N] -----------------
template<int MODE>
__global__ __launch_bounds__(256) void k_gemm(
    const unsigned short* __restrict__ A,
    const unsigned short* __restrict__ W,
    const int M, const int N, const int K,
    unsigned short* __restrict__ outb,
    float* __restrict__ resid,
    const unsigned short* __restrict__ bias,
    const int* __restrict__ flag)
{
  __shared__ __align__(16) short a_sh[64][40];
  __shared__ __align__(16) short b_sh[64][40];
  const int t    = threadIdx.x;
  const int m0   = blockIdx.y * 64;
  const int n0   = blockIdx.x * 64;
  const int wv   = t >> 6;
  const int lane = t & 63;
  const int l16  = lane & 15;
  const int quad = lane >> 4;
  const int am = t >> 2, ak = (t & 3) << 3;
  const int bk = t >> 3, bn = (t & 7) << 3;
  f4v acc[4] = {};
  for (int k0 = 0; k0 < K; k0 += 32) {
    s8v av = *(const s8v*)(A + (size_t)(m0 + am) * K + k0 + ak);
    *(s8v*)(&a_sh[am][ak]) = av;
    s8v bv = *(const s8v*)(W + (size_t)(k0 + bk) * N + n0 + bn);
    #pragma unroll
    for (int j = 0; j < 8; j++) b_sh[bn + j][bk] = bv[j];
    __syncthreads();
    const s8v af = *(const s8v*)(&a_sh[wv * 16 + l16][quad * 8]);
    #pragma unroll
    for (int nt = 0; nt < 4; nt++) {
      const s8v bf = *(const s8v*)(&b_sh[nt * 16 + l16][quad * 8]);
      acc[nt] = __builtin_amdgcn_mfma_f32_16x16x32_bf16(af, bf, acc[nt], 0, 0, 0);
    }
    __syncthreads();
  }
  const int fv = (MODE == 2) ? *flag : 0;
  #pragma unroll
  for (int nt = 0; nt < 4; nt++) {
    #pragma unroll
    for (int r = 0; r < 4; r++) {
      const int m = m0 + wv * 16 + quad * 4 + r;
      const int n = n0 + nt * 16 + l16;
      float v = acc[nt][r];
      if (MODE == 0) {
        if (n < 2304) outb[(size_t)m * DINPROJ + n] = f2b(v);
      } else if (MODE == 1) {
        resid[(size_t)m * N + n] += v;
      } else {
        v += b2f(bias[n]);
        if (fv) outb[(size_t)m * N + n] = f2b(v);
        else    ((float*)resid)[(size_t)m * N + n] = v;
      }
    }
  }
}

// ---------------- causal conv1d (K=4) + silu -> bf16 -----------------------
__global__ __launch_bounds__(256) void k_conv(
    const unsigned short* __restrict__ zx,
    const unsigned short* __restrict__ cw,
    const unsigned short* __restrict__ cb,
    unsigned short* __restrict__ out)
{
  const int c   = blockIdx.x * 256 + threadIdx.x;
  const int tok = blockIdx.y;
  const int l   = tok & (L_ - 1);
  const int base = tok - l;
  float acc = b2f(cb[c]);
  #pragma unroll
  for (int k = 0; k < 4; k++) {
    const int li = l + k - 3;
    if (li >= 0)
      acc = fmaf(b2f(zx[(size_t)(base + li) * DINPROJ + DINNER + c]),
                 b2f(cw[c * 4 + k]), acc);
  }
  out[(size_t)tok * CONVDIM + c] = f2b(acc / (1.f + expf(-acc)));
}

// ---------------- dt = softplus(raw + bias); decay = exp(dt * -exp(Alog)) --
__global__ __launch_bounds__(256) void k_dtdecay(
    const float* __restrict__ raw,
    const float* __restrict__ dtb,
    const float* __restrict__ alog,
    float* __restrict__ DT, float* __restrict__ DEC)
{
  const int idx = blockIdx.x * 256 + threadIdx.x;
  const int h = idx & 15;
  float x = raw[idx] + dtb[h];
  float dt = (x > 20.f) ? x : log1pf(expf(x));
  float A = -expf(alog[h]);
  DT[idx] = dt;
  DEC[idx] = expf(dt * A);
}

// ---------------- legacy sequential scan (ws_size fallback) ----------------
__global__ __launch_bounds__(256) void k_scan(
    const unsigned short* __restrict__ xbc,
    const float* __restrict__ DT,
    const float* __restrict__ DEC,
    const float* __restrict__ Dp,
    unsigned short* __restrict__ yout)
{
  const int bh = blockIdx.x;
  const int b  = bh >> 4, h = bh & 15;
  const int t  = threadIdx.x;
  __shared__ __align__(16) float sxbc[320];
  __shared__ float ssc[2];
  const int ngrp = t & 15, pgrp = t >> 4;
  const int n0 = ngrp * 8, p0 = pgrp * 4;
  float hs[4][8] = {};
  const float Dh = Dp[h];
  for (int ts = 0; ts < L_; ts++) {
    const int tok = (b << 10) + ts;
    if (t < 40) {
      const int j = t * 8;
      const int col = (j < 64) ? (h * HEADDIM + j) : (960 + j);
      u8v v = *(const u8v*)(xbc + (size_t)tok * CONVDIM + col);
      float* d = &sxbc[j];
      #pragma unroll
      for (int q = 0; q < 8; q++) d[q] = b2f(v[q]);
    }
    if (t == 63) {
      ssc[0] = DT[(size_t)tok * NHEADS + h];
      ssc[1] = DEC[(size_t)tok * NHEADS + h];
    }
    __syncthreads();
    float xa[4]; *(float4*)xa = *(const float4*)&sxbc[p0];
    float Bv[8], Cv[8];
    #pragma unroll
    for (int q = 0; q < 8; q++) { Bv[q] = sxbc[64 + n0 + q]; Cv[q] = sxbc[192 + n0 + q]; }
    const float dts = ssc[0], dec = ssc[1];
    float yp[4];
    #pragma unroll
    for (int p = 0; p < 4; p++) {
      const float dtx = dts * xa[p];
      float a = 0.f;
      #pragma unroll
      for (int n = 0; n < 8; n++) {
        hs[p][n] = fmaf(hs[p][n], dec, dtx * Bv[n]);
        a = fmaf(hs[p][n], Cv[n], a);
      }
      yp[p] = a;
    }
    #pragma unroll
    for (int m = 1; m < 16; m <<= 1) {
      #pragma unroll
      for (int p = 0; p < 4; p++) yp[p] += __shfl_xor(yp[p], m);
    }
    if (ngrp == 0) {
      ushort4 o;
      o.x = f2b(yp[0] + Dh * xa[0]);
      o.y = f2b(yp[1] + Dh * xa[1]);
      o.z = f2b(yp[2] + Dh * xa[2]);
      o.w = f2b(yp[3] + Dh * xa[3]);
      *(ushort4*)(yout + (size_t)tok * DINPROJ + DINNER + h * HEADDIM + p0) = o;
    }
    __syncthreads();
  }
}

// ---------------- pass A: local chunk scan ---------------------------------
// grid (NC, 256): blockIdx.x = chunk c, blockIdx.y = bh.
// Writes y_local (incl D*x) to yout, end-state bf16 [p][n] to SLOC slot
// (bh*NC+c), running decay product P_t to PP.
__global__ __launch_bounds__(256) void k_scan_chunk(
    const unsigned short* __restrict__ xbc,
    const float* __restrict__ DT,
    const float* __restrict__ DEC,
    const float* __restrict__ Dp,
    unsigned short* __restrict__ yout,
    unsigned short* __restrict__ SLOC,
    float* __restrict__ PP)
{
  const int c  = blockIdx.x;
  const int bh = blockIdx.y;
  const int b  = bh >> 4, h = bh & 15;
  const int t  = threadIdx.x;
  __shared__ __align__(16) float sxbc[320];
  __shared__ float ssc[2];
  const int ngrp = t & 15, pgrp = t >> 4;
  const int n0 = ngrp * 8, p0 = pgrp * 4;
  float hs[4][8] = {};
  const float Dh = Dp[h];
  float cumP = 1.f;
  const int tok0 = (b << 10) + c * LC;
  for (int s = 0; s < LC; s++) {
    const int tok = tok0 + s;
    if (t < 40) {
      const int j = t * 8;
      const int col = (j < 64) ? (h * HEADDIM + j) : (960 + j);
      u8v v = *(const u8v*)(xbc + (size_t)tok * CONVDIM + col);
      float* d = &sxbc[j];
      #pragma unroll
      for (int q = 0; q < 8; q++) d[q] = b2f(v[q]);
    }
    if (t == 63) {
      ssc[0] = DT[(size_t)tok * NHEADS + h];
      ssc[1] = DEC[(size_t)tok * NHEADS + h];
    }
    __syncthreads();
    float xa[4]; *(float4*)xa = *(const float4*)&sxbc[p0];
    float Bv[8], Cv[8];
    #pragma unroll
    for (int q = 0; q < 8; q++) { Bv[q] = sxbc[64 + n0 + q]; Cv[q] = sxbc[192 + n0 + q]; }
    const float dts = ssc[0], dec = ssc[1];
    cumP *= dec;
    if (t == 0) PP[(size_t)(bh * NC + c) * LC + s] = cumP;
    float yp[4];
    #pragma unroll
    for (int p = 0; p < 4; p++) {
      const float dtx = dts * xa[p];
      float a = 0.f;
      #pragma unroll
      for (int n = 0; n < 8; n++) {
        hs[p][n] = fmaf(hs[p][n], dec, dtx * Bv[n]);
        a = fmaf(hs[p][n], Cv[n], a);
      }
      yp[p] = a;
    }
    #pragma unroll
    for (int m = 1; m < 16; m <<= 1) {
      #pragma unroll
      for (int p = 0; p < 4; p++) yp[p] += __shfl_xor(yp[p], m);
    }
    if (ngrp == 0) {
      ushort4 o;
      o.x = f2b(yp[0] + Dh * xa[0]);
      o.y = f2b(yp[1] + Dh * xa[1]);
      o.z = f2b(yp[2] + Dh * xa[2]);
      o.w = f2b(yp[3] + Dh * xa[3]);
      *(ushort4*)(yout + (size_t)tok * DINPROJ + DINNER + h * HEADDIM + p0) = o;
    }
    __syncthreads();
  }
  // end-state -> SLOC slot (bh*NC+c), layout [p (64 rows)][n (128 cols)] bf16
  unsigned short* dst = SLOC + (((size_t)(bh * NC + c)) << 13);
  #pragma unroll
  for (int p = 0; p < 4; p++) {
    u8v o;
    #pragma unroll
    for (int j = 0; j < 8; j++) o[j] = f2b(hs[p][j]);
    *(u8v*)(dst + (p0 + p) * DSTATE + n0) = o;
  }
}

// ---------------- pass B: inter-chunk state propagation --------------------
// grid 256 (bh). hstart_{c+1} = D_c*hstart_c + hend_c ; stored into slot c.
// (So slot c holds h_start for chunk c+1; chunk 0 has h_start = 0.)
__global__ __launch_bounds__(256) void k_scan_prop(
    unsigned short* __restrict__ SLOC,
    const float* __restrict__ PP)
{
  const int bh = blockIdx.x;
  const int t  = threadIdx.x;
  float hst[32];
  #pragma unroll
  for (int j = 0; j < 32; j++) hst[j] = 0.f;
  for (int c = 0; c < NC - 1; c++) {
    const size_t slot = ((size_t)(bh * NC + c)) << 13;
    const float Dc = PP[(size_t)(bh * NC + c) * LC + (LC - 1)];
    unsigned short* base = SLOC + slot + t * 32;
    u8v v[4];
    #pragma unroll
    for (int j = 0; j < 4; j++) v[j] = *(const u8v*)(base + j * 8);
    #pragma unroll
    for (int j = 0; j < 32; j++)
      hst[j] = fmaf(hst[j], Dc, b2f(v[j >> 3][j & 7]));
    #pragma unroll
    for (int j = 0; j < 4; j++) {
      u8v o;
      #pragma unroll
      for (int q = 0; q < 8; q++) o[q] = f2b(hst[j * 8 + q]);
      *(u8v*)(base + j * 8) = o;
    }
  }
}

// ---------------- pass C: y += P_t * (C_t . h_start)  via MFMA -------------
// grid (NC-1, 256): blockIdx.x+1 = chunk c (1..NC-1), blockIdx.y = bh.
// D[tok][p] = sum_n C[tok][n] * hstart[p][n]; A-frags from conv buffer,
// B-frags straight from SLOC (layout [p][n] == [n_out][k]).
__global__ __launch_bounds__(256) void k_scan_ystate(
    const unsigned short* __restrict__ xbc,
    const unsigned short* __restrict__ SLOC,
    const float* __restrict__ PP,
    unsigned short* __restrict__ yout)
{
  const int c  = blockIdx.x + 1;
  const int bh = blockIdx.y;
  const int b  = bh >> 4, h = bh & 15;
  const int t  = threadIdx.x;
  const int wv = t >> 6, lane = t & 63;
  const int l16 = lane & 15, quad = lane >> 4;
  __shared__ float sp[LC];
  if (t < LC) sp[t] = PP[(size_t)(bh * NC + c) * LC + t];
  __syncthreads();
  const int tok0 = (b << 10) + c * LC;
  const unsigned short* hsrc = SLOC + (((size_t)(bh * NC + c - 1)) << 13);
  f4v acc[2][4] = {};
  for (int k0 = 0; k0 < DSTATE; k0 += 32) {
    s8v af[2], bf[4];
    #pragma unroll
    for (int i = 0; i < 2; i++) {
      const int m = wv * 32 + i * 16 + l16;   // token within chunk
      af[i] = *(const s8v*)(xbc + (size_t)(tok0 + m) * CONVDIM + 1152 + k0 + quad * 8);
    }
    #pragma unroll
    for (int nt = 0; nt < 4; nt++)
      bf[nt] = *(const s8v*)(hsrc + (nt * 16 + l16) * DSTATE + k0 + quad * 8);
    #pragma unroll
    for (int i = 0; i < 2; i++)
      #pragma unroll
      for (int nt = 0; nt < 4; nt++)
        acc[i][nt] = __builtin_amdgcn_mfma_f32_16x16x32_bf16(af[i], bf[nt], acc[i][nt], 0, 0, 0);
  }
  #pragma unroll
  for (int i = 0; i < 2; i++) {
    #pragma unroll
    for (int nt = 0; nt < 4; nt++) {
      #pragma unroll
      for (int r = 0; r < 4; r++) {
        const int m = wv * 32 + i * 16 + quad * 4 + r;
        const int p = nt * 16 + l16;
        unsigned short* yp = yout + (size_t)(tok0 + m) * DINPROJ + DINNER + h * HEADDIM + p;
        *yp = f2b(b2f(*yp) + sp[m] * acc[i][nt][r]);
      }
    }
  }
}

// ---------------- y*silu(z) -> RMSnorm*rms_w -> bf16 -----------------------
__global__ __launch_bounds__(256) void k_gate_rms(
    const unsigned short* __restrict__ buf1,
    const unsigned short* __restrict__ rmsw,
    unsigned short* __restrict__ out)
{
  const int tok = blockIdx.x;
  const int t   = threadIdx.x;
  const int c   = t * 4;
  ushort4 z4 = *(const ushort4*)(buf1 + (size_t)tok * DINPROJ + c);
  ushort4 y4 = *(const ushort4*)(buf1 + (size_t)tok * DINPROJ + DINNER + c);
  const unsigned short* za = (const unsigned short*)&z4;
  const unsigned short* ya = (const unsigned short*)&y4;
  float gv[4];
  #pragma unroll
  for (int j = 0; j < 4; j++) {
    float z = b2f(za[j]), y = b2f(ya[j]);
    gv[j] = y * (z / (1.f + expf(-z)));
  }
  float sq = gv[0]*gv[0] + gv[1]*gv[1] + gv[2]*gv[2] + gv[3]*gv[3];
  #pragma unroll
  for (int m = 1; m < 64; m <<= 1) sq += __shfl_xor(sq, m);
  __shared__ float sm[4];
  if ((t & 63) == 0) sm[t >> 6] = sq;
  __syncthreads();
  float rs = rsqrtf((sm[0] + sm[1] + sm[2] + sm[3]) * (1.f / DINNER) + 1e-5f);
  ushort4 o;
  unsigned short* oa = (unsigned short*)&o;
  #pragma unroll
  for (int j = 0; j < 4; j++) oa[j] = f2b(gv[j] * rs * b2f(rmsw[c + j]));
  *(ushort4*)(out + (size_t)tok * DINNER + c) = o;
}

// ---------------------------------------------------------------------------
extern "C" void kernel_launch(void* const* d_in, const int* in_sizes, int n_in,
                              void* d_out, int out_size, void* d_ws, size_t ws_size,
                              hipStream_t stream)
{
  (void)in_sizes; (void)n_in; (void)out_size;

  char* ws = (char*)d_ws;
  float*          X       = (float*)(ws);                        // 33,554,432 B
  unsigned short* BUF1    = (unsigned short*)(ws + 33554432);    // 76,021,760 B
  unsigned short* BUF2    = (unsigned short*)(ws + 109576192);   // 41,943,040 B
  float*          DTRAW   = (float*)(ws + 151519232);            //  1,048,576 B
  float*          DT      = (float*)(ws + 152567808);
  float*          DEC     = (float*)(ws + 153616384);
  unsigned short* CWIN    = (unsigned short*)(ws + 154664960);   // 14,548,992 B
  unsigned short* CWOUT   = (unsigned short*)(ws + 169213952);   //  6,291,456 B
  unsigned short* CWFIN   = (unsigned short*)(ws + 175505408);   //    524,288 B
  unsigned short* CIPW    = (unsigned short*)(ws + 176029696);   //     17,408 B
  unsigned short* CSTATES = (unsigned short*)(ws + 176047104);   //    557,056 B
  unsigned short* CSMALL  = (unsigned short*)(ws + 176604160);   //    105,472 B
  float*          CF32    = (float*)(ws + 176709632);            //      1,152 B
  int*            FLAG    = (int*)(ws + 176710784);
  unsigned short* SLOC    = (unsigned short*)(ws + 176711680);   // 33,554,432 B
  float*          PP      = (float*)(ws + 210266112);            //  1,048,576 B
  const bool usechunk = (ws_size >= 211314688ull);               // end of PP
  unsigned short* HN      = BUF2;

  unsigned short* Cipb   = CSMALL + 0;
  unsigned short* Clng   = CSMALL + 512;
  unsigned short* Clnb   = CSMALL + 3584;
  unsigned short* Cconvw = CSMALL + 6656;
  unsigned short* Cconvb = CSMALL + 37376;
  unsigned short* Crmsw  = CSMALL + 45056;
  unsigned short* Cpostg = CSMALL + 51200;
  unsigned short* Cpostb = CSMALL + 51712;
  unsigned short* Cfinb  = CSMALL + 52224;
  float* Cdtb  = CF32 + 0;
  float* Calog = CF32 + 96;
  float* Cdpar = CF32 + 192;

  k_flag<<<1, 1, 0, stream>>>((const unsigned int*)d_in[3], FLAG);
  k_convert<<<512, 256, 0, stream>>>(d_in[0],  CSTATES, NTOK * 17, FLAG);
  k_convert<<<64, 256, 0, stream>>>(d_in[1],  CIPW,    17 * DMODEL, FLAG);
  k_convert<<<4,  256, 0, stream>>>(d_in[2],  Cipb,    DMODEL, FLAG);
  k_convert<<<16, 256, 0, stream>>>(d_in[3],  Clng,    NLAYERS * DMODEL, FLAG);
  k_convert<<<16, 256, 0, stream>>>(d_in[4],  Clnb,    NLAYERS * DMODEL, FLAG);
  k_convert_pad<<<2048, 256, 0, stream>>>(d_in[5], CWIN, FLAG);
  k_convert<<<128, 256, 0, stream>>>(d_in[6], Cconvw,  NLAYERS * CONVDIM * 4, FLAG);
  k_convert<<<32, 256, 0, stream>>>(d_in[7],  Cconvb,  NLAYERS * CONVDIM, FLAG);
  k_convertf<<<1, 256, 0, stream>>>(d_in[8],  Cdtb,    NLAYERS * NHEADS, FLAG);
  k_convertf<<<1, 256, 0, stream>>>(d_in[9],  Calog,   NLAYERS * NHEADS, FLAG);
  k_convertf<<<1, 256, 0, stream>>>(d_in[10], Cdpar,   NLAYERS * NHEADS, FLAG);
  k_convert<<<32, 256, 0, stream>>>(d_in[11], Crmsw,   NLAYERS * DINNER, FLAG);
  k_convert<<<2048, 256, 0, stream>>>(d_in[12], CWOUT, NLAYERS * DINNER * DMODEL, FLAG);
  k_convert<<<4,  256, 0, stream>>>(d_in[13], Cpostg,  DMODEL, FLAG);
  k_convert<<<4,  256, 0, stream>>>(d_in[14], Cpostb,  DMODEL, FLAG);
  k_convert<<<512, 256, 0, stream>>>(d_in[15], CWFIN,  DMODEL * DMODEL, FLAG);
  k_convert<<<4,  256, 0, stream>>>(d_in[16], Cfinb,   DMODEL, FLAG);

  k_inproj_rope<<<NTOK, 256, 0, stream>>>(CSTATES, CIPW, Cipb, X);

  for (int l = 0; l < NLAYERS; l++) {
    k_layernorm<<<NTOK, 64, 0, stream>>>(X, Clng + l * DMODEL, Clnb + l * DMODEL, HN);
    k_gemm<0><<<dim3(NPAD / 64, NTOK / 64), 256, 0, stream>>>(
        HN, CWIN + (size_t)l * DMODEL * NPAD, NTOK, NPAD, DMODEL,
        BUF1, nullptr, nullptr, FLAG);
    k_dtgemv<<<NTOK, 64, 0, stream>>>(
        X, Clng + l * DMODEL, Clnb + l * DMODEL,
        CWIN + (size_t)l * DMODEL * NPAD, DTRAW);
    k_conv<<<dim3(CONVDIM / 256, NTOK), 256, 0, stream>>>(
        BUF1, Cconvw + l * CONVDIM * 4, Cconvb + l * CONVDIM, BUF2);
    k_dtdecay<<<NTOK * NHEADS / 256, 256, 0, stream>>>(
        DTRAW, Cdtb + l * NHEADS, Calog + l * NHEADS, DT, DEC);
    if (usechunk) {
      k_scan_chunk<<<dim3(NC, 256), 256, 0, stream>>>(
          BUF2, DT, DEC, Cdpar + l * NHEADS, BUF1, SLOC, PP);
      k_scan_prop<<<256, 256, 0, stream>>>(SLOC, PP);
      k_scan_ystate<<<dim3(NC - 1, 256), 256, 0, stream>>>(BUF2, SLOC, PP, BUF1);
    } else {
      k_scan<<<256, 256, 0, stream>>>(BUF2, DT, DEC, Cdpar + l * NHEADS, BUF1);
    }
    k_gate_rms<<<NTOK, 256, 0, stream>>>(BUF1, Crmsw + l * DINNER, HN);
    k_gemm<1><<<dim3(DMODEL / 64, NTOK / 64), 256, 0, stream>>>(
        HN, CWOUT + (size_t)l * DINNER * DMODEL, NTOK, DMODEL, DINNER,
        nullptr, X, nullptr, FLAG);
  }

  k_layernorm<<<NTOK, 64, 0, stream>>>(X, Cpostg, Cpostb, HN);
  k_gemm<2><<<dim3(DMODEL / 64, NTOK / 64), 256, 0, stream>>>(
      HN, CWFIN, NTOK, DMODEL, DMODEL,
      (unsigned short*)d_out, (float*)d_out, Cfinb, FLAG);
}

// Round 4
// 3795.740 us; speedup vs baseline: 2.5192x; 1.4481x over previous
//
#include <hip/hip_runtime.h>
#include <hip/hip_bf16.h>
#include <cstdint>
#include <cstddef>

// ---------------------------------------------------------------------------
// Mamba2 encoder, MI355X. Round 4: MFMA chunked scan (Mamba2 dual form).
//   pass A (new): per (b,h,chunk=128):  G = C·B^T (MFMA) -> S = mask(G)*M*dt
//                 -> Y = X^T-staged MFMA;  h_end via w3-weighted MFMA.
//                 4 barriers/block instead of 256.
//   pass B / pass C / GEMMs / conv / norms unchanged from round 3.
// ---------------------------------------------------------------------------

#define B_      16
#define L_      1024
#define NTOK    (B_ * L_)      // 16384
#define DMODEL  512
#define DINNER  1024
#define NHEADS  16
#define HEADDIM 64
#define DSTATE  128
#define CONVDIM 1280           // DINNER + 2*DSTATE
#define DINPROJ 2320           // 2*DINNER + 2*DSTATE + NHEADS
#define NPAD    2368           // 37*64, padded in_proj N
#define NLAYERS 6
#define LC      128            // scan chunk length
#define NC      8              // chunks per sequence (L_/LC)
#define SP      136            // padded LDS row stride (shorts)

typedef short s8v  __attribute__((ext_vector_type(8)));
typedef float f4v  __attribute__((ext_vector_type(4)));
typedef unsigned short u8v __attribute__((ext_vector_type(8)));

__device__ __forceinline__ float b2f(unsigned short u) {
  unsigned v = ((unsigned)u) << 16;
  return __builtin_bit_cast(float, v);
}
__device__ __forceinline__ unsigned short f2b(float f) {
  unsigned u = __builtin_bit_cast(unsigned, f);
  u += 0x7fffu + ((u >> 16) & 1u);
  return (unsigned short)(u >> 16);
}

// ---------------- dtype probe: ln_g[0] == 1.0 ------------------------------
__global__ void k_flag(const unsigned int* __restrict__ lng_raw, int* __restrict__ flag) {
  *flag = (lng_raw[0] == 0x3F800000u) ? 0 : 1;   // fp32 1.0 vs two bf16 1.0
}

// ---------------- canonicalize: any -> bf16 --------------------------------
__global__ __launch_bounds__(256) void k_convert(
    const void* __restrict__ src, unsigned short* __restrict__ dst,
    const int n, const int* __restrict__ flag)
{
  const int f = *flag;
  for (int i = blockIdx.x * 256 + threadIdx.x; i < n; i += gridDim.x * 256)
    dst[i] = f ? ((const unsigned short*)src)[i] : f2b(((const float*)src)[i]);
}

// ---------------- canonicalize: any -> fp32 --------------------------------
__global__ __launch_bounds__(256) void k_convertf(
    const void* __restrict__ src, float* __restrict__ dst,
    const int n, const int* __restrict__ flag)
{
  const int f = *flag;
  for (int i = blockIdx.x * 256 + threadIdx.x; i < n; i += gridDim.x * 256)
    dst[i] = f ? b2f(((const unsigned short*)src)[i]) : ((const float*)src)[i];
}

// ---------------- canonicalize in_proj_w with column pad to NPAD -----------
__global__ __launch_bounds__(256) void k_convert_pad(
    const void* __restrict__ src, unsigned short* __restrict__ dst,
    const int* __restrict__ flag)
{
  const int n = NLAYERS * DMODEL * NPAD;
  const int f = *flag;
  for (int i = blockIdx.x * 256 + threadIdx.x; i < n; i += gridDim.x * 256) {
    const int row = i / NPAD, col = i - row * NPAD;
    unsigned short v = 0;
    if (col < DINPROJ) {
      const size_t s = (size_t)row * DINPROJ + col;
      v = f ? ((const unsigned short*)src)[s] : f2b(((const float*)src)[s]);
    }
    dst[i] = v;
  }
}

// ---------------- prologue: x = rope(states @ W + b) -----------------------
__global__ __launch_bounds__(256) void k_inproj_rope(
    const unsigned short* __restrict__ states,
    const unsigned short* __restrict__ W,
    const unsigned short* __restrict__ bias,
    float* __restrict__ X)
{
  const int tok = blockIdx.x;
  const int t   = threadIdx.x;
  __shared__ float s[17];
  if (t < 17) s[t] = b2f(states[tok * 17 + t]);
  __syncthreads();
  const int d0 = 2 * t, d1 = d0 + 1;
  float x1 = b2f(bias[d0]);
  float x2 = b2f(bias[d1]);
  #pragma unroll
  for (int k = 0; k < 17; k++) {
    float sv = s[k];
    x1 = fmaf(sv, b2f(W[k * DMODEL + d0]), x1);
    x2 = fmaf(sv, b2f(W[k * DMODEL + d1]), x2);
  }
  const int l = tok & (L_ - 1);
  float invf = expf(-((float)d0 / (float)DMODEL) * 9.2103403719761836f);
  float fr = (float)l * invf;
  float sn, c;
  sincosf(fr, &sn, &c);
  X[(size_t)tok * DMODEL + d0] = x1 * c - x2 * sn;
  X[(size_t)tok * DMODEL + d1] = x1 * sn + x2 * c;
}

// ---------------- layernorm (fp32 in, bf16 out) ----------------------------
__global__ __launch_bounds__(64) void k_layernorm(
    const float* __restrict__ X,
    const unsigned short* __restrict__ g,
    const unsigned short* __restrict__ b,
    unsigned short* __restrict__ out)
{
  const int tok = blockIdx.x;
  const int t   = threadIdx.x;
  const float* row = X + (size_t)tok * DMODEL;
  float4 v0 = *(const float4*)(row + t * 4);
  float4 v1 = *(const float4*)(row + 256 + t * 4);
  float s  = v0.x + v0.y + v0.z + v0.w + v1.x + v1.y + v1.z + v1.w;
  float sq = v0.x*v0.x + v0.y*v0.y + v0.z*v0.z + v0.w*v0.w
           + v1.x*v1.x + v1.y*v1.y + v1.z*v1.z + v1.w*v1.w;
  #pragma unroll
  for (int m = 1; m < 64; m <<= 1) { s += __shfl_xor(s, m); sq += __shfl_xor(sq, m); }
  float mu  = s  * (1.f / DMODEL);
  float var = sq * (1.f / DMODEL) - mu * mu;
  float rs  = rsqrtf(var + 1e-5f);
  {
    int c = t * 4;
    ushort4 o;
    o.x = f2b((v0.x - mu) * rs * b2f(g[c+0]) + b2f(b[c+0]));
    o.y = f2b((v0.y - mu) * rs * b2f(g[c+1]) + b2f(b[c+1]));
    o.z = f2b((v0.z - mu) * rs * b2f(g[c+2]) + b2f(b[c+2]));
    o.w = f2b((v0.w - mu) * rs * b2f(g[c+3]) + b2f(b[c+3]));
    *(ushort4*)(out + (size_t)tok * DMODEL + c) = o;
  }
  {
    int c = 256 + t * 4;
    ushort4 o;
    o.x = f2b((v1.x - mu) * rs * b2f(g[c+0]) + b2f(b[c+0]));
    o.y = f2b((v1.y - mu) * rs * b2f(g[c+1]) + b2f(b[c+1]));
    o.z = f2b((v1.z - mu) * rs * b2f(g[c+2]) + b2f(b[c+2]));
    o.w = f2b((v1.w - mu) * rs * b2f(g[c+3]) + b2f(b[c+3]));
    *(ushort4*)(out + (size_t)tok * DMODEL + c) = o;
  }
}

// ---------------- fp32 GEMV for the 16 dt columns (precision-critical) -----
__global__ __launch_bounds__(64) void k_dtgemv(
    const float* __restrict__ X,
    const unsigned short* __restrict__ g,
    const unsigned short* __restrict__ b,
    const unsigned short* __restrict__ W,       // canonical padded [512,NPAD]
    float* __restrict__ dtraw)
{
  const int tok = blockIdx.x;
  const int t   = threadIdx.x;
  __shared__ __align__(16) float sx[DMODEL];
  const float* row = X + (size_t)tok * DMODEL;
  float4 v0 = *(const float4*)(row + t * 4);
  float4 v1 = *(const float4*)(row + 256 + t * 4);
  *(float4*)&sx[t * 4]       = v0;
  *(float4*)&sx[256 + t * 4] = v1;
  float s  = v0.x + v0.y + v0.z + v0.w + v1.x + v1.y + v1.z + v1.w;
  float sq = v0.x*v0.x + v0.y*v0.y + v0.z*v0.z + v0.w*v0.w
           + v1.x*v1.x + v1.y*v1.y + v1.z*v1.z + v1.w*v1.w;
  #pragma unroll
  for (int m = 1; m < 64; m <<= 1) { s += __shfl_xor(s, m); sq += __shfl_xor(sq, m); }
  float mu  = s  * (1.f / DMODEL);
  float var = sq * (1.f / DMODEL) - mu * mu;
  float rs  = rsqrtf(var + 1e-5f);
  __syncthreads();
  const int hc = t & 15;
  const int kq = t >> 4;
  float acc = 0.f;
  for (int k = kq * 128; k < kq * 128 + 128; k++) {
    float xn = (sx[k] - mu) * rs * b2f(g[k]) + b2f(b[k]);
    acc = fmaf(xn, b2f(W[(size_t)k * NPAD + 2304 + hc]), acc);
  }
  acc += __shfl_xor(acc, 16);
  acc += __shfl_xor(acc, 32);
  if (kq == 0) dtraw[(size_t)tok * NHEADS + hc] = acc;
}

// ---------------- MFMA bf16 GEMM: C[M,N] = A[M,K] @ W[K,N] -----------------
template<int MODE>
__global__ __launch_bounds__(256) void k_gemm(
    const unsigned short* __restrict__ A,
    const unsigned short* __restrict__ W,
    const int M, const int N, const int K,
    unsigned short* __restrict__ outb,
    float* __restrict__ resid,
    const unsigned short* __restrict__ bias,
    const int* __restrict__ flag)
{
  __shared__ __align__(16) short a_sh[64][40];
  __shared__ __align__(16) short b_sh[64][40];
  const int t    = threadIdx.x;
  const int m0   = blockIdx.y * 64;
  const int n0   = blockIdx.x * 64;
  const int wv   = t >> 6;
  const int lane = t & 63;
  const int l16  = lane & 15;
  const int quad = lane >> 4;
  const int am = t >> 2, ak = (t & 3) << 3;
  const int bk = t >> 3, bn = (t & 7) << 3;
  f4v acc[4] = {};
  for (int k0 = 0; k0 < K; k0 += 32) {
    s8v av = *(const s8v*)(A + (size_t)(m0 + am) * K + k0 + ak);
    *(s8v*)(&a_sh[am][ak]) = av;
    s8v bv = *(const s8v*)(W + (size_t)(k0 + bk) * N + n0 + bn);
    #pragma unroll
    for (int j = 0; j < 8; j++) b_sh[bn + j][bk] = bv[j];
    __syncthreads();
    const s8v af = *(const s8v*)(&a_sh[wv * 16 + l16][quad * 8]);
    #pragma unroll
    for (int nt = 0; nt < 4; nt++) {
      const s8v bf = *(const s8v*)(&b_sh[nt * 16 + l16][quad * 8]);
      acc[nt] = __builtin_amdgcn_mfma_f32_16x16x32_bf16(af, bf, acc[nt], 0, 0, 0);
    }
    __syncthreads();
  }
  const int fv = (MODE == 2) ? *flag : 0;
  #pragma unroll
  for (int nt = 0; nt < 4; nt++) {
    #pragma unroll
    for (int r = 0; r < 4; r++) {
      const int m = m0 + wv * 16 + quad * 4 + r;
      const int n = n0 + nt * 16 + l16;
      float v = acc[nt][r];
      if (MODE == 0) {
        if (n < 2304) outb[(size_t)m * DINPROJ + n] = f2b(v);
      } else if (MODE == 1) {
        resid[(size_t)m * N + n] += v;
      } else {
        v += b2f(bias[n]);
        if (fv) outb[(size_t)m * N + n] = f2b(v);
        else    ((float*)resid)[(size_t)m * N + n] = v;
      }
    }
  }
}

// ---------------- causal conv1d (K=4) + silu -> bf16 -----------------------
__global__ __launch_bounds__(256) void k_conv(
    const unsigned short* __restrict__ zx,
    const unsigned short* __restrict__ cw,
    const unsigned short* __restrict__ cb,
    unsigned short* __restrict__ out)
{
  const int c   = blockIdx.x * 256 + threadIdx.x;
  const int tok = blockIdx.y;
  const int l   = tok & (L_ - 1);
  const int base = tok - l;
  float acc = b2f(cb[c]);
  #pragma unroll
  for (int k = 0; k < 4; k++) {
    const int li = l + k - 3;
    if (li >= 0)
      acc = fmaf(b2f(zx[(size_t)(base + li) * DINPROJ + DINNER + c]),
                 b2f(cw[c * 4 + k]), acc);
  }
  out[(size_t)tok * CONVDIM + c] = f2b(acc / (1.f + expf(-acc)));
}

// ---------------- dt = softplus(raw + bias); decay = exp(dt * -exp(Alog)) --
__global__ __launch_bounds__(256) void k_dtdecay(
    const float* __restrict__ raw,
    const float* __restrict__ dtb,
    const float* __restrict__ alog,
    float* __restrict__ DT, float* __restrict__ DEC)
{
  const int idx = blockIdx.x * 256 + threadIdx.x;
  const int h = idx & 15;
  float x = raw[idx] + dtb[h];
  float dt = (x > 20.f) ? x : log1pf(expf(x));
  float A = -expf(alog[h]);
  DT[idx] = dt;
  DEC[idx] = expf(dt * A);
}

// ---------------- legacy sequential scan (ws_size fallback) ----------------
__global__ __launch_bounds__(256) void k_scan(
    const unsigned short* __restrict__ xbc,
    const float* __restrict__ DT,
    const float* __restrict__ DEC,
    const float* __restrict__ Dp,
    unsigned short* __restrict__ yout)
{
  const int bh = blockIdx.x;
  const int b  = bh >> 4, h = bh & 15;
  const int t  = threadIdx.x;
  __shared__ __align__(16) float sxbc[320];
  __shared__ float ssc[2];
  const int ngrp = t & 15, pgrp = t >> 4;
  const int n0 = ngrp * 8, p0 = pgrp * 4;
  float hs[4][8] = {};
  const float Dh = Dp[h];
  for (int ts = 0; ts < L_; ts++) {
    const int tok = (b << 10) + ts;
    if (t < 40) {
      const int j = t * 8;
      const int col = (j < 64) ? (h * HEADDIM + j) : (960 + j);
      u8v v = *(const u8v*)(xbc + (size_t)tok * CONVDIM + col);
      float* d = &sxbc[j];
      #pragma unroll
      for (int q = 0; q < 8; q++) d[q] = b2f(v[q]);
    }
    if (t == 63) {
      ssc[0] = DT[(size_t)tok * NHEADS + h];
      ssc[1] = DEC[(size_t)tok * NHEADS + h];
    }
    __syncthreads();
    float xa[4]; *(float4*)xa = *(const float4*)&sxbc[p0];
    float Bv[8], Cv[8];
    #pragma unroll
    for (int q = 0; q < 8; q++) { Bv[q] = sxbc[64 + n0 + q]; Cv[q] = sxbc[192 + n0 + q]; }
    const float dts = ssc[0], dec = ssc[1];
    float yp[4];
    #pragma unroll
    for (int p = 0; p < 4; p++) {
      const float dtx = dts * xa[p];
      float a = 0.f;
      #pragma unroll
      for (int n = 0; n < 8; n++) {
        hs[p][n] = fmaf(hs[p][n], dec, dtx * Bv[n]);
        a = fmaf(hs[p][n], Cv[n], a);
      }
      yp[p] = a;
    }
    #pragma unroll
    for (int m = 1; m < 16; m <<= 1) {
      #pragma unroll
      for (int p = 0; p < 4; p++) yp[p] += __shfl_xor(yp[p], m);
    }
    if (ngrp == 0) {
      ushort4 o;
      o.x = f2b(yp[0] + Dh * xa[0]);
      o.y = f2b(yp[1] + Dh * xa[1]);
      o.z = f2b(yp[2] + Dh * xa[2]);
      o.w = f2b(yp[3] + Dh * xa[3]);
      *(ushort4*)(yout + (size_t)tok * DINPROJ + DINNER + h * HEADDIM + p0) = o;
    }
    __syncthreads();
  }
}

// ---------------- pass A (MFMA): local chunk scan --------------------------
// grid (NC, 256): blockIdx.x = chunk c, blockIdx.y = bh. 256 threads/4 waves.
// Y_local[t][p] = sum_{s<=t} exp(Lc[t]-Lc[s]) dt_s (C_t.B_s) x_s[p] + Dh x_t[p]
// h_end[p][n]   = sum_s dt_s exp(Lc[127]-Lc[s]) x_s[p] B_s[n]
// where Lc = in-chunk cumsum of dt*A. S matrix staged bf16 through LDS.
__global__ __launch_bounds__(256) void k_scan_chunk_mfma(
    const unsigned short* __restrict__ xbc,
    const float* __restrict__ DT,
    const float* __restrict__ alog,   // per-layer [16]
    const float* __restrict__ Dp,     // per-layer [16]
    unsigned short* __restrict__ yout,
    unsigned short* __restrict__ SLOC,
    float* __restrict__ PP)
{
  const int c  = blockIdx.x;
  const int bh = blockIdx.y;
  const int b  = bh >> 4, h = bh & 15;
  const int t  = threadIdx.x;
  const int wv = t >> 6, lane = t & 63;
  const int l16 = lane & 15, quad = lane >> 4;
  const int tok0 = (b << 10) + c * LC;

  // sBig: first B^T [n][s], then (after step-3) the masked S [t][s]
  __shared__ __align__(16) short sBig[128][SP];   // 34,816 B
  __shared__ __align__(16) short sXt[64][SP];     // 17,408 B  x^T [p][s]
  __shared__ float sLc[128], sdt[128], sw3[128];  //  1,536 B

  // ---- stage 1: dt cumsum (wave 0) + X^T/B^T staging (all threads) --------
  if (wv == 0) {
    float d0 = DT[(size_t)(tok0 + lane) * NHEADS + h];
    float d1 = DT[(size_t)(tok0 + 64 + lane) * NHEADS + h];
    float v = d0;
    #pragma unroll
    for (int off = 1; off < 64; off <<= 1) {
      float u = __shfl_up(v, off);
      if (lane >= off) v += u;
    }
    float tot = __shfl(v, 63);
    float w = d1;
    #pragma unroll
    for (int off = 1; off < 64; off <<= 1) {
      float u = __shfl_up(w, off);
      if (lane >= off) w += u;
    }
    w += tot;
    const float A = -expf(alog[h]);
    sdt[lane] = d0;  sdt[64 + lane] = d1;
    sLc[lane] = A * v;  sLc[64 + lane] = A * w;
  }
  {
    const int s0   = (t & 63) * 2;
    const int part = t >> 6;
    const unsigned short* r0 = xbc + (size_t)(tok0 + s0) * CONVDIM;
    const unsigned short* r1 = r0 + CONVDIM;
    // X^T: p-range part*16..+16
    u8v xa0 = *(const u8v*)(r0 + h * 64 + part * 16);
    u8v xa1 = *(const u8v*)(r0 + h * 64 + part * 16 + 8);
    u8v xb0 = *(const u8v*)(r1 + h * 64 + part * 16);
    u8v xb1 = *(const u8v*)(r1 + h * 64 + part * 16 + 8);
    #pragma unroll
    for (int j = 0; j < 16; j++) {
      unsigned lo = (j < 8) ? (unsigned)xa0[j] : (unsigned)xa1[j - 8];
      unsigned hi = (j < 8) ? (unsigned)xb0[j] : (unsigned)xb1[j - 8];
      *(unsigned*)&sXt[part * 16 + j][s0] = lo | (hi << 16);
    }
    // B^T: n-range part*32..+32 -> sBig
    #pragma unroll
    for (int q = 0; q < 4; q++) {
      u8v b0 = *(const u8v*)(r0 + 1024 + part * 32 + q * 8);
      u8v b1 = *(const u8v*)(r1 + 1024 + part * 32 + q * 8);
      #pragma unroll
      for (int j = 0; j < 8; j++)
        *(unsigned*)&sBig[part * 32 + q * 8 + j][s0] =
            ((unsigned)b0[j]) | (((unsigned)b1[j]) << 16);
    }
  }
  __syncthreads();

  // ---- stage 2: w3 + PP ----------------------------------------------------
  if (t < 128) {
    sw3[t] = sdt[t] * expf(sLc[127] - sLc[t]);
    PP[(size_t)(bh * NC + c) * LC + t] = expf(sLc[t]);
  }
  __syncthreads();

  // ---- stage 3: h_end[p][n] -> SLOC (uses sBig as B^T) --------------------
  {
    unsigned short* dst = SLOC + (((size_t)(bh * NC + c)) << 13);
    #pragma unroll
    for (int sel = 0; sel < 2; sel++) {
      const int nt = 2 * wv + sel;
      const int ncol = nt * 16 + l16;
      f4v acc[4] = {};
      #pragma unroll
      for (int kk = 0; kk < 4; kk++) {
        s8v bb = *(const s8v*)&sBig[ncol][kk * 32 + quad * 8];
        float4 w0 = *(const float4*)&sw3[kk * 32 + quad * 8];
        float4 w1 = *(const float4*)&sw3[kk * 32 + quad * 8 + 4];
        s8v bw;
        bw[0] = (short)f2b(b2f((unsigned short)bb[0]) * w0.x);
        bw[1] = (short)f2b(b2f((unsigned short)bb[1]) * w0.y);
        bw[2] = (short)f2b(b2f((unsigned short)bb[2]) * w0.z);
        bw[3] = (short)f2b(b2f((unsigned short)bb[3]) * w0.w);
        bw[4] = (short)f2b(b2f((unsigned short)bb[4]) * w1.x);
        bw[5] = (short)f2b(b2f((unsigned short)bb[5]) * w1.y);
        bw[6] = (short)f2b(b2f((unsigned short)bb[6]) * w1.z);
        bw[7] = (short)f2b(b2f((unsigned short)bb[7]) * w1.w);
        #pragma unroll
        for (int pt = 0; pt < 4; pt++) {
          s8v ax = *(const s8v*)&sXt[pt * 16 + l16][kk * 32 + quad * 8];
          acc[pt] = __builtin_amdgcn_mfma_f32_16x16x32_bf16(ax, bw, acc[pt], 0, 0, 0);
        }
      }
      #pragma unroll
      for (int pt = 0; pt < 4; pt++)
        #pragma unroll
        for (int r = 0; r < 4; r++)
          dst[(pt * 16 + quad * 4 + r) * DSTATE + ncol] = f2b(acc[pt][r]);
    }
  }
  __syncthreads();

  // ---- stage 4: G = C.B^T, mask*M*dt -> sBig as S[t][s] (bf16) ------------
  {
    #pragma unroll
    for (int sel = 0; sel < 2; sel++) {
      const int tt = sel ? (7 - wv) : wv;
      const int trow = tok0 + tt * 16 + l16;
      s8v af[4];
      #pragma unroll
      for (int kk = 0; kk < 4; kk++)
        af[kk] = *(const s8v*)(xbc + (size_t)trow * CONVDIM + 1152 + kk * 32 + quad * 8);
      for (int st = 0; st <= tt; st++) {
        const int srow = tok0 + st * 16 + l16;
        f4v acc = {};
        #pragma unroll
        for (int kk = 0; kk < 4; kk++) {
          s8v bf = *(const s8v*)(xbc + (size_t)srow * CONVDIM + 1024 + kk * 32 + quad * 8);
          acc = __builtin_amdgcn_mfma_f32_16x16x32_bf16(af[kk], bf, acc, 0, 0, 0);
        }
        const int scol = st * 16 + l16;
        const float Ls = sLc[scol], dts = sdt[scol];
        #pragma unroll
        for (int r = 0; r < 4; r++) {
          const int trw = tt * 16 + quad * 4 + r;
          const float mv = (scol <= trw) ? expf(sLc[trw] - Ls) * dts : 0.f;
          sBig[trw][scol] = (short)f2b(acc[r] * mv);
        }
      }
      if ((tt & 1) == 0) {   // zero the read-but-unwritten above-diag tile
        #pragma unroll
        for (int r = 0; r < 4; r++)
          sBig[tt * 16 + quad * 4 + r][(tt + 1) * 16 + l16] = 0;
      }
    }
  }
  __syncthreads();

  // ---- stage 5: Y^T = X^T @ S^T (A=sXt, B=sS rows), + Dh*x, store ---------
  {
    const float Dh = Dp[h];
    #pragma unroll
    for (int sel = 0; sel < 2; sel++) {
      const int tt = sel ? (7 - wv) : wv;
      const int nk = tt / 2 + 1;
      const int tcol = tt * 16 + l16;
      f4v acc[4] = {};
      for (int kk = 0; kk < nk; kk++) {
        s8v bf = *(const s8v*)&sBig[tcol][kk * 32 + quad * 8];
        #pragma unroll
        for (int pt = 0; pt < 4; pt++) {
          s8v ax = *(const s8v*)&sXt[pt * 16 + l16][kk * 32 + quad * 8];
          acc[pt] = __builtin_amdgcn_mfma_f32_16x16x32_bf16(ax, bf, acc[pt], 0, 0, 0);
        }
      }
      const int tok = tok0 + tcol;
      unsigned short* yrow = yout + (size_t)tok * DINPROJ + DINNER + h * 64;
      #pragma unroll
      for (int pt = 0; pt < 4; pt++) {
        ushort4 o;
        unsigned short* oa = (unsigned short*)&o;
        #pragma unroll
        for (int r = 0; r < 4; r++) {
          const int p = pt * 16 + quad * 4 + r;
          oa[r] = f2b(acc[pt][r] + Dh * b2f((unsigned short)sXt[p][tcol]));
        }
        *(ushort4*)(yrow + pt * 16 + quad * 4) = o;
      }
    }
  }
}

// ---------------- pass B: inter-chunk state propagation --------------------
__global__ __launch_bounds__(256) void k_scan_prop(
    unsigned short* __restrict__ SLOC,
    const float* __restrict__ PP)
{
  const int bh = blockIdx.x;
  const int t  = threadIdx.x;
  float hst[32];
  #pragma unroll
  for (int j = 0; j < 32; j++) hst[j] = 0.f;
  for (int c = 0; c < NC - 1; c++) {
    const size_t slot = ((size_t)(bh * NC + c)) << 13;
    const float Dc = PP[(size_t)(bh * NC + c) * LC + (LC - 1)];
    unsigned short* base = SLOC + slot + t * 32;
    u8v v[4];
    #pragma unroll
    for (int j = 0; j < 4; j++) v[j] = *(const u8v*)(base + j * 8);
    #pragma unroll
    for (int j = 0; j < 32; j++)
      hst[j] = fmaf(hst[j], Dc, b2f(v[j >> 3][j & 7]));
    #pragma unroll
    for (int j = 0; j < 4; j++) {
      u8v o;
      #pragma unroll
      for (int q = 0; q < 8; q++) o[q] = f2b(hst[j * 8 + q]);
      *(u8v*)(base + j * 8) = o;
    }
  }
}

// ---------------- pass C: y += P_t * (C_t . h_start)  via MFMA -------------
__global__ __launch_bounds__(256) void k_scan_ystate(
    const unsigned short* __restrict__ xbc,
    const unsigned short* __restrict__ SLOC,
    const float* __restrict__ PP,
    unsigned short* __restrict__ yout)
{
  const int c  = blockIdx.x + 1;
  const int bh = blockIdx.y;
  const int b  = bh >> 4, h = bh & 15;
  const int t  = threadIdx.x;
  const int wv = t >> 6, lane = t & 63;
  const int l16 = lane & 15, quad = lane >> 4;
  __shared__ float sp[LC];
  if (t < LC) sp[t] = PP[(size_t)(bh * NC + c) * LC + t];
  __syncthreads();
  const int tok0 = (b << 10) + c * LC;
  const unsigned short* hsrc = SLOC + (((size_t)(bh * NC + c - 1)) << 13);
  f4v acc[2][4] = {};
  for (int k0 = 0; k0 < DSTATE; k0 += 32) {
    s8v af[2], bf[4];
    #pragma unroll
    for (int i = 0; i < 2; i++) {
      const int m = wv * 32 + i * 16 + l16;
      af[i] = *(const s8v*)(xbc + (size_t)(tok0 + m) * CONVDIM + 1152 + k0 + quad * 8);
    }
    #pragma unroll
    for (int nt = 0; nt < 4; nt++)
      bf[nt] = *(const s8v*)(hsrc + (nt * 16 + l16) * DSTATE + k0 + quad * 8);
    #pragma unroll
    for (int i = 0; i < 2; i++)
      #pragma unroll
      for (int nt = 0; nt < 4; nt++)
        acc[i][nt] = __builtin_amdgcn_mfma_f32_16x16x32_bf16(af[i], bf[nt], acc[i][nt], 0, 0, 0);
  }
  #pragma unroll
  for (int i = 0; i < 2; i++) {
    #pragma unroll
    for (int nt = 0; nt < 4; nt++) {
      #pragma unroll
      for (int r = 0; r < 4; r++) {
        const int m = wv * 32 + i * 16 + quad * 4 + r;
        const int p = nt * 16 + l16;
        unsigned short* yp = yout + (size_t)(tok0 + m) * DINPROJ + DINNER + h * HEADDIM + p;
        *yp = f2b(b2f(*yp) + sp[m] * acc[i][nt][r]);
      }
    }
  }
}

// ---------------- y*silu(z) -> RMSnorm*rms_w -> bf16 -----------------------
__global__ __launch_bounds__(256) void k_gate_rms(
    const unsigned short* __restrict__ buf1,
    const unsigned short* __restrict__ rmsw,
    unsigned short* __restrict__ out)
{
  const int tok = blockIdx.x;
  const int t   = threadIdx.x;
  const int c   = t * 4;
  ushort4 z4 = *(const ushort4*)(buf1 + (size_t)tok * DINPROJ + c);
  ushort4 y4 = *(const ushort4*)(buf1 + (size_t)tok * DINPROJ + DINNER + c);
  const unsigned short* za = (const unsigned short*)&z4;
  const unsigned short* ya = (const unsigned short*)&y4;
  float gv[4];
  #pragma unroll
  for (int j = 0; j < 4; j++) {
    float z = b2f(za[j]), y = b2f(ya[j]);
    gv[j] = y * (z / (1.f + expf(-z)));
  }
  float sq = gv[0]*gv[0] + gv[1]*gv[1] + gv[2]*gv[2] + gv[3]*gv[3];
  #pragma unroll
  for (int m = 1; m < 64; m <<= 1) sq += __shfl_xor(sq, m);
  __shared__ float sm[4];
  if ((t & 63) == 0) sm[t >> 6] = sq;
  __syncthreads();
  float rs = rsqrtf((sm[0] + sm[1] + sm[2] + sm[3]) * (1.f / DINNER) + 1e-5f);
  ushort4 o;
  unsigned short* oa = (unsigned short*)&o;
  #pragma unroll
  for (int j = 0; j < 4; j++) oa[j] = f2b(gv[j] * rs * b2f(rmsw[c + j]));
  *(ushort4*)(out + (size_t)tok * DINNER + c) = o;
}

// ---------------------------------------------------------------------------
extern "C" void kernel_launch(void* const* d_in, const int* in_sizes, int n_in,
                              void* d_out, int out_size, void* d_ws, size_t ws_size,
                              hipStream_t stream)
{
  (void)in_sizes; (void)n_in; (void)out_size;

  char* ws = (char*)d_ws;
  float*          X       = (float*)(ws);                        // 33,554,432 B
  unsigned short* BUF1    = (unsigned short*)(ws + 33554432);    // 76,021,760 B
  unsigned short* BUF2    = (unsigned short*)(ws + 109576192);   // 41,943,040 B
  float*          DTRAW   = (float*)(ws + 151519232);            //  1,048,576 B
  float*          DT      = (float*)(ws + 152567808);
  float*          DEC     = (float*)(ws + 153616384);
  unsigned short* CWIN    = (unsigned short*)(ws + 154664960);   // 14,548,992 B
  unsigned short* CWOUT   = (unsigned short*)(ws + 169213952);   //  6,291,456 B
  unsigned short* CWFIN   = (unsigned short*)(ws + 175505408);   //    524,288 B
  unsigned short* CIPW    = (unsigned short*)(ws + 176029696);   //     17,408 B
  unsigned short* CSTATES = (unsigned short*)(ws + 176047104);   //    557,056 B
  unsigned short* CSMALL  = (unsigned short*)(ws + 176604160);   //    105,472 B
  float*          CF32    = (float*)(ws + 176709632);            //      1,152 B
  int*            FLAG    = (int*)(ws + 176710784);
  unsigned short* SLOC    = (unsigned short*)(ws + 176711680);   // 33,554,432 B
  float*          PP      = (float*)(ws + 210266112);            //  1,048,576 B
  const bool usechunk = (ws_size >= 211314688ull);
  unsigned short* HN      = BUF2;

  unsigned short* Cipb   = CSMALL + 0;
  unsigned short* Clng   = CSMALL + 512;
  unsigned short* Clnb   = CSMALL + 3584;
  unsigned short* Cconvw = CSMALL + 6656;
  unsigned short* Cconvb = CSMALL + 37376;
  unsigned short* Crmsw  = CSMALL + 45056;
  unsigned short* Cpostg = CSMALL + 51200;
  unsigned short* Cpostb = CSMALL + 51712;
  unsigned short* Cfinb  = CSMALL + 52224;
  float* Cdtb  = CF32 + 0;
  float* Calog = CF32 + 96;
  float* Cdpar = CF32 + 192;

  k_flag<<<1, 1, 0, stream>>>((const unsigned int*)d_in[3], FLAG);
  k_convert<<<512, 256, 0, stream>>>(d_in[0],  CSTATES, NTOK * 17, FLAG);
  k_convert<<<64, 256, 0, stream>>>(d_in[1],  CIPW,    17 * DMODEL, FLAG);
  k_convert<<<4,  256, 0, stream>>>(d_in[2],  Cipb,    DMODEL, FLAG);
  k_convert<<<16, 256, 0, stream>>>(d_in[3],  Clng,    NLAYERS * DMODEL, FLAG);
  k_convert<<<16, 256, 0, stream>>>(d_in[4],  Clnb,    NLAYERS * DMODEL, FLAG);
  k_convert_pad<<<2048, 256, 0, stream>>>(d_in[5], CWIN, FLAG);
  k_convert<<<128, 256, 0, stream>>>(d_in[6], Cconvw,  NLAYERS * CONVDIM * 4, FLAG);
  k_convert<<<32, 256, 0, stream>>>(d_in[7],  Cconvb,  NLAYERS * CONVDIM, FLAG);
  k_convertf<<<1, 256, 0, stream>>>(d_in[8],  Cdtb,    NLAYERS * NHEADS, FLAG);
  k_convertf<<<1, 256, 0, stream>>>(d_in[9],  Calog,   NLAYERS * NHEADS, FLAG);
  k_convertf<<<1, 256, 0, stream>>>(d_in[10], Cdpar,   NLAYERS * NHEADS, FLAG);
  k_convert<<<32, 256, 0, stream>>>(d_in[11], Crmsw,   NLAYERS * DINNER, FLAG);
  k_convert<<<2048, 256, 0, stream>>>(d_in[12], CWOUT, NLAYERS * DINNER * DMODEL, FLAG);
  k_convert<<<4,  256, 0, stream>>>(d_in[13], Cpostg,  DMODEL, FLAG);
  k_convert<<<4,  256, 0, stream>>>(d_in[14], Cpostb,  DMODEL, FLAG);
  k_convert<<<512, 256, 0, stream>>>(d_in[15], CWFIN,  DMODEL * DMODEL, FLAG);
  k_convert<<<4,  256, 0, stream>>>(d_in[16], Cfinb,   DMODEL, FLAG);

  k_inproj_rope<<<NTOK, 256, 0, stream>>>(CSTATES, CIPW, Cipb, X);

  for (int l = 0; l < NLAYERS; l++) {
    k_layernorm<<<NTOK, 64, 0, stream>>>(X, Clng + l * DMODEL, Clnb + l * DMODEL, HN);
    k_gemm<0><<<dim3(NPAD / 64, NTOK / 64), 256, 0, stream>>>(
        HN, CWIN + (size_t)l * DMODEL * NPAD, NTOK, NPAD, DMODEL,
        BUF1, nullptr, nullptr, FLAG);
    k_dtgemv<<<NTOK, 64, 0, stream>>>(
        X, Clng + l * DMODEL, Clnb + l * DMODEL,
        CWIN + (size_t)l * DMODEL * NPAD, DTRAW);
    k_conv<<<dim3(CONVDIM / 256, NTOK), 256, 0, stream>>>(
        BUF1, Cconvw + l * CONVDIM * 4, Cconvb + l * CONVDIM, BUF2);
    k_dtdecay<<<NTOK * NHEADS / 256, 256, 0, stream>>>(
        DTRAW, Cdtb + l * NHEADS, Calog + l * NHEADS, DT, DEC);
    if (usechunk) {
      k_scan_chunk_mfma<<<dim3(NC, 256), 256, 0, stream>>>(
          BUF2, DT, Calog + l * NHEADS, Cdpar + l * NHEADS, BUF1, SLOC, PP);
      k_scan_prop<<<256, 256, 0, stream>>>(SLOC, PP);
      k_scan_ystate<<<dim3(NC - 1, 256), 256, 0, stream>>>(BUF2, SLOC, PP, BUF1);
    } else {
      k_scan<<<256, 256, 0, stream>>>(BUF2, DT, DEC, Cdpar + l * NHEADS, BUF1);
    }
    k_gate_rms<<<NTOK, 256, 0, stream>>>(BUF1, Crmsw + l * DINNER, HN);
    k_gemm<1><<<dim3(DMODEL / 64, NTOK / 64), 256, 0, stream>>>(
        HN, CWOUT + (size_t)l * DINNER * DMODEL, NTOK, DMODEL, DINNER,
        nullptr, X, nullptr, FLAG);
  }

  k_layernorm<<<NTOK, 64, 0, stream>>>(X, Cpostg, Cpostb, HN);
  k_gemm<2><<<dim3(DMODEL / 64, NTOK / 64), 256, 0, stream>>>(
      HN, CWFIN, NTOK, DMODEL, DMODEL,
      (unsigned short*)d_out, (float*)d_out, Cfinb, FLAG);
}